// Round 1
// baseline (1540.431 us; speedup 1.0000x reference)
//
#include <hip/hip_runtime.h>
#include <hip/hip_bf16.h>

#define SEQ 8
#define H 512
#define EPS 1e-5f
#define NROWS 65536

typedef __hip_bfloat16 bf16;

// ---------------------------------------------------------------------------
// K1: per-row (wave-per-row) LayerNorm + neighbor attention softmax + pool.
// Writes fused = node + sum_s atten[s]*neighbor[s] as bf16 [NROWS][H].
// Note: logits = neighbor@W_n + (node@W_t) + b; the node term and bias are
// constant across the softmax axis -> exactly cancel. We skip them.
// ---------------------------------------------------------------------------
__global__ __launch_bounds__(256) void k1_ln_attn_pool(
    const float* __restrict__ x,
    const float* __restrict__ gamma,
    const float* __restrict__ beta,
    const float* __restrict__ attn_W,
    bf16* __restrict__ fused)
{
    const int lane = threadIdx.x & 63;
    const int wave = threadIdx.x >> 6;
    const long row = (long)blockIdx.x * 4 + wave;
    const int h0 = lane << 2;            // columns h0..h0+3 and h0+256..h0+259

    const float* xr = x + row * (long)(SEQ * H);

    // Load the full 8x512 row: lane holds 8 columns (2 float4 per seq pos).
    float xv[SEQ][8];
#pragma unroll
    for (int s = 0; s < SEQ; ++s) {
        float4 a = *(const float4*)(xr + s * H + h0);
        float4 b = *(const float4*)(xr + s * H + 256 + h0);
        xv[s][0] = a.x; xv[s][1] = a.y; xv[s][2] = a.z; xv[s][3] = a.w;
        xv[s][4] = b.x; xv[s][5] = b.y; xv[s][6] = b.z; xv[s][7] = b.w;
    }

    float gg[8], bb[8], wn[8];
    {
        float4 a = *(const float4*)(gamma + h0);
        float4 b = *(const float4*)(gamma + 256 + h0);
        gg[0]=a.x; gg[1]=a.y; gg[2]=a.z; gg[3]=a.w;
        gg[4]=b.x; gg[5]=b.y; gg[6]=b.z; gg[7]=b.w;
        a = *(const float4*)(beta + h0);
        b = *(const float4*)(beta + 256 + h0);
        bb[0]=a.x; bb[1]=a.y; bb[2]=a.z; bb[3]=a.w;
        bb[4]=b.x; bb[5]=b.y; bb[6]=b.z; bb[7]=b.w;
        a = *(const float4*)(attn_W + H + h0);        // W_n = attn_W[H:]
        b = *(const float4*)(attn_W + H + 256 + h0);
        wn[0]=a.x; wn[1]=a.y; wn[2]=a.z; wn[3]=a.w;
        wn[4]=b.x; wn[5]=b.y; wn[6]=b.z; wn[7]=b.w;
    }

    // LayerNorm stats per seq position (wave butterfly reduction over 512)
    float rstd[SEQ], nmr[SEQ];
#pragma unroll
    for (int s = 0; s < SEQ; ++s) {
        float sum = 0.0f, sq = 0.0f;
#pragma unroll
        for (int i = 0; i < 8; ++i) {
            sum += xv[s][i];
            sq = fmaf(xv[s][i], xv[s][i], sq);
        }
#pragma unroll
        for (int off = 32; off > 0; off >>= 1) {
            sum += __shfl_xor(sum, off, 64);
            sq  += __shfl_xor(sq,  off, 64);
        }
        float m = sum * (1.0f / H);
        float v = fmaf(-m, m, sq * (1.0f / H));
        float r = rsqrtf(v + EPS);
        rstd[s] = r;
        nmr[s]  = -m * r;
    }

    // nrm(s,i) = ((x - mean)*rstd)*gamma + beta = fma(fma(x, rstd, -m*rstd), g, b)
#define NRM(s, i) fmaf(fmaf(xv[s][i], rstd[s], nmr[s]), gg[i], bb[i])

    // neighbor logits (s = 1..7), softmax
    float att[SEQ];
#pragma unroll
    for (int s = 1; s < SEQ; ++s) {
        float p = 0.0f;
#pragma unroll
        for (int i = 0; i < 8; ++i) p = fmaf(NRM(s, i), wn[i], p);
#pragma unroll
        for (int off = 32; off > 0; off >>= 1) p += __shfl_xor(p, off, 64);
        att[s] = p;
    }
    float mx = att[1];
#pragma unroll
    for (int s = 2; s < SEQ; ++s) mx = fmaxf(mx, att[s]);
    float den = 0.0f;
#pragma unroll
    for (int s = 1; s < SEQ; ++s) { att[s] = __expf(att[s] - mx); den += att[s]; }
    float rden = 1.0f / den;
#pragma unroll
    for (int s = 1; s < SEQ; ++s) att[s] *= rden;

    // fused = node + sum_s att[s] * neighbor[s]; store bf16
    union { ushort4 u[2]; bf16 h[8]; } ow;
#pragma unroll
    for (int i = 0; i < 8; ++i) {
        float f = NRM(0, i);
#pragma unroll
        for (int s = 1; s < SEQ; ++s) f = fmaf(att[s], NRM(s, i), f);
        ow.h[i] = __float2bfloat16(f);
    }
#undef NRM
    *(ushort4*)(fused + row * H + h0)       = ow.u[0];
    *(ushort4*)(fused + row * H + 256 + h0) = ow.u[1];
}

// ---------------------------------------------------------------------------
// K2: out = relu(fused @ out_W + out_b), fused bf16 [NROWS][512],
// out_W fp32 [512][256]. Classic SGEMM: 64x256 block tile, Kc=32,
// 8x8 register tile per thread (256 threads).
// ---------------------------------------------------------------------------
__global__ __launch_bounds__(256) void k2_gemm_relu(
    const bf16* __restrict__ A,
    const float* __restrict__ W,
    const float* __restrict__ bias,
    float* __restrict__ out)
{
    __shared__ float Al[32 * 64];     // [k][r]  (A transposed)
    __shared__ float Bl[32 * 256];    // [k][j]

    const int tid = threadIdx.x;
    const long row0 = (long)blockIdx.x * 64;

    const int tj = tid & 31;          // 32 j-groups of 8
    const int tr = tid >> 5;          // 8 r-groups of 8
    const int j0 = tj * 8;
    const int r0 = tr * 8;

    float acc[8][8];
#pragma unroll
    for (int i = 0; i < 8; ++i)
#pragma unroll
        for (int j = 0; j < 8; ++j) acc[i][j] = 0.0f;

    const int a_row = tid >> 2;           // 0..63
    const int a_k   = (tid & 3) * 8;      // 0,8,16,24
    const bf16* a_src = A + (row0 + a_row) * (long)H + a_k;

    for (int kc = 0; kc < H; kc += 32) {
        // stage A chunk (bf16 -> fp32, transposed into [k][row])
        uint4 araw = *(const uint4*)(a_src + kc);   // 8 bf16
#pragma unroll
        for (int q = 0; q < 4; ++q) {
            unsigned int w = (&araw.x)[q];
            Al[(a_k + 2*q    ) * 64 + a_row] = __uint_as_float(w << 16);
            Al[(a_k + 2*q + 1) * 64 + a_row] = __uint_as_float(w & 0xffff0000u);
        }
        // stage B chunk (32 x 256 fp32), linear float4 copy
        const float4* bsrc = (const float4*)(W + (long)kc * 256);
        float4* bdst = (float4*)Bl;
#pragma unroll
        for (int i = 0; i < 8; ++i) bdst[tid + i * 256] = bsrc[tid + i * 256];
        __syncthreads();

#pragma unroll
        for (int k = 0; k < 32; ++k) {
            float4 a0 = *(const float4*)&Al[k * 64 + r0];
            float4 a1 = *(const float4*)&Al[k * 64 + r0 + 4];
            float4 b0 = *(const float4*)&Bl[k * 256 + j0];
            float4 b1 = *(const float4*)&Bl[k * 256 + j0 + 4];
            float a_[8] = {a0.x, a0.y, a0.z, a0.w, a1.x, a1.y, a1.z, a1.w};
            float b_[8] = {b0.x, b0.y, b0.z, b0.w, b1.x, b1.y, b1.z, b1.w};
#pragma unroll
            for (int i = 0; i < 8; ++i)
#pragma unroll
                for (int j = 0; j < 8; ++j)
                    acc[i][j] = fmaf(a_[i], b_[j], acc[i][j]);
        }
        __syncthreads();
    }

    float bsr[8];
    {
        float4 c0 = *(const float4*)(bias + j0);
        float4 c1 = *(const float4*)(bias + j0 + 4);
        bsr[0]=c0.x; bsr[1]=c0.y; bsr[2]=c0.z; bsr[3]=c0.w;
        bsr[4]=c1.x; bsr[5]=c1.y; bsr[6]=c1.z; bsr[7]=c1.w;
    }
#pragma unroll
    for (int i = 0; i < 8; ++i) {
        float o[8];
#pragma unroll
        for (int j = 0; j < 8; ++j) o[j] = fmaxf(acc[i][j] + bsr[j], 0.0f);
        float* dst = out + (row0 + r0 + i) * 256 + j0;
        *(float4*)dst       = make_float4(o[0], o[1], o[2], o[3]);
        *(float4*)(dst + 4) = make_float4(o[4], o[5], o[6], o[7]);
    }
}

extern "C" void kernel_launch(void* const* d_in, const int* in_sizes, int n_in,
                              void* d_out, int out_size, void* d_ws, size_t ws_size,
                              hipStream_t stream) {
    const float* x      = (const float*)d_in[0];
    const float* gamma  = (const float*)d_in[1];
    const float* beta   = (const float*)d_in[2];
    const float* attn_W = (const float*)d_in[3];
    // d_in[4] = attn_b: unused (exactly cancels in softmax)
    const float* out_W  = (const float*)d_in[5];
    const float* out_b  = (const float*)d_in[6];
    float* out = (float*)d_out;
    bf16* fused = (bf16*)d_ws;   // 65536*512*2 = 64 MiB scratch

    k1_ln_attn_pool<<<NROWS / 4, 256, 0, stream>>>(x, gamma, beta, attn_W, fused);
    k2_gemm_relu<<<NROWS / 64, 256, 0, stream>>>(fused, out_W, out_b, out);
}

// Round 2
// 1407.997 us; speedup vs baseline: 1.0941x; 1.0941x over previous
//
#include <hip/hip_runtime.h>
#include <hip/hip_bf16.h>

#define SEQ 8
#define H 512
#define EPS 1e-5f
#define NROWS 65536
#define NOUT 256

typedef __hip_bfloat16 bf16;
typedef __attribute__((ext_vector_type(8))) short bf16x8;   // 8 bf16 = 4 VGPRs
typedef __attribute__((ext_vector_type(4))) float f32x4;

#define GLOAD_LDS16(g, l)                                               \
    __builtin_amdgcn_global_load_lds(                                   \
        (const __attribute__((address_space(1))) unsigned int*)(g),     \
        (__attribute__((address_space(3))) unsigned int*)(l), 16, 0, 0)

// ---------------------------------------------------------------------------
// K0: convert + transpose out_W fp32 [512][256] -> Wt bf16 [256][512]
// (k-contiguous per n, so K2 can stage B with global_load_lds width-16).
// 16384 threads, each writes 8 contiguous bf16 (16 B coalesced store).
// ---------------------------------------------------------------------------
__global__ __launch_bounds__(64) void k0_convW(const float* __restrict__ W,
                                               bf16* __restrict__ Wt)
{
    const int u = blockIdx.x * 64 + threadIdx.x;   // 0..16383
    const int n = u >> 6;                          // 0..255
    const int k0 = (u & 63) * 8;                   // 0..504
    bf16 tmp[8];
#pragma unroll
    for (int i = 0; i < 8; ++i)
        tmp[i] = __float2bfloat16(W[(long)(k0 + i) * NOUT + n]);
    *(ushort4*)(Wt + (long)n * H + k0)     = *(ushort4*)&tmp[0];
    *(ushort4*)(Wt + (long)n * H + k0 + 4) = *(ushort4*)&tmp[4];
}

// ---------------------------------------------------------------------------
// K1: per-row (wave-per-row) LayerNorm + neighbor attention softmax + pool.
// Writes fused = node + sum_s atten[s]*neighbor[s] as bf16 [NROWS][H].
// logits node-term + bias are constant over the softmax axis -> cancel.
// ---------------------------------------------------------------------------
__global__ __launch_bounds__(256) void k1_ln_attn_pool(
    const float* __restrict__ x,
    const float* __restrict__ gamma,
    const float* __restrict__ beta,
    const float* __restrict__ attn_W,
    bf16* __restrict__ fused)
{
    const int lane = threadIdx.x & 63;
    const int wave = threadIdx.x >> 6;
    const long row = (long)blockIdx.x * 4 + wave;
    const int h0 = lane << 2;

    const float* xr = x + row * (long)(SEQ * H);

    float xv[SEQ][8];
#pragma unroll
    for (int s = 0; s < SEQ; ++s) {
        float4 a = *(const float4*)(xr + s * H + h0);
        float4 b = *(const float4*)(xr + s * H + 256 + h0);
        xv[s][0] = a.x; xv[s][1] = a.y; xv[s][2] = a.z; xv[s][3] = a.w;
        xv[s][4] = b.x; xv[s][5] = b.y; xv[s][6] = b.z; xv[s][7] = b.w;
    }

    float gg[8], bb[8], wn[8];
    {
        float4 a = *(const float4*)(gamma + h0);
        float4 b = *(const float4*)(gamma + 256 + h0);
        gg[0]=a.x; gg[1]=a.y; gg[2]=a.z; gg[3]=a.w;
        gg[4]=b.x; gg[5]=b.y; gg[6]=b.z; gg[7]=b.w;
        a = *(const float4*)(beta + h0);
        b = *(const float4*)(beta + 256 + h0);
        bb[0]=a.x; bb[1]=a.y; bb[2]=a.z; bb[3]=a.w;
        bb[4]=b.x; bb[5]=b.y; bb[6]=b.z; bb[7]=b.w;
        a = *(const float4*)(attn_W + H + h0);
        b = *(const float4*)(attn_W + H + 256 + h0);
        wn[0]=a.x; wn[1]=a.y; wn[2]=a.z; wn[3]=a.w;
        wn[4]=b.x; wn[5]=b.y; wn[6]=b.z; wn[7]=b.w;
    }

    float rstd[SEQ], nmr[SEQ];
#pragma unroll
    for (int s = 0; s < SEQ; ++s) {
        float sum = 0.0f, sq = 0.0f;
#pragma unroll
        for (int i = 0; i < 8; ++i) {
            sum += xv[s][i];
            sq = fmaf(xv[s][i], xv[s][i], sq);
        }
#pragma unroll
        for (int off = 32; off > 0; off >>= 1) {
            sum += __shfl_xor(sum, off, 64);
            sq  += __shfl_xor(sq,  off, 64);
        }
        float m = sum * (1.0f / H);
        float v = fmaf(-m, m, sq * (1.0f / H));
        float r = rsqrtf(v + EPS);
        rstd[s] = r;
        nmr[s]  = -m * r;
    }

#define NRM(s, i) fmaf(fmaf(xv[s][i], rstd[s], nmr[s]), gg[i], bb[i])

    float att[SEQ];
#pragma unroll
    for (int s = 1; s < SEQ; ++s) {
        float p = 0.0f;
#pragma unroll
        for (int i = 0; i < 8; ++i) p = fmaf(NRM(s, i), wn[i], p);
#pragma unroll
        for (int off = 32; off > 0; off >>= 1) p += __shfl_xor(p, off, 64);
        att[s] = p;
    }
    float mx = att[1];
#pragma unroll
    for (int s = 2; s < SEQ; ++s) mx = fmaxf(mx, att[s]);
    float den = 0.0f;
#pragma unroll
    for (int s = 1; s < SEQ; ++s) { att[s] = __expf(att[s] - mx); den += att[s]; }
    float rden = 1.0f / den;
#pragma unroll
    for (int s = 1; s < SEQ; ++s) att[s] *= rden;

    union { ushort4 u[2]; bf16 h[8]; } ow;
#pragma unroll
    for (int i = 0; i < 8; ++i) {
        float f = NRM(0, i);
#pragma unroll
        for (int s = 1; s < SEQ; ++s) f = fmaf(att[s], NRM(s, i), f);
        ow.h[i] = __float2bfloat16(f);
    }
#undef NRM
    *(ushort4*)(fused + row * H + h0)       = ow.u[0];
    *(ushort4*)(fused + row * H + 256 + h0) = ow.u[1];
}

// ---------------------------------------------------------------------------
// K2: out = relu(fused @ out_W + out_b) via bf16 MFMA.
// fused bf16 [65536][512], Wt bf16 [256][512] (pre-transposed), out fp32.
// Block = 256 thr (4 waves) -> 128x128 tile; wave = 64x64 (4x4 of 16x16x32).
// LDS layout (kb, m, j): kb = k-octet (0..3), m = tile row (0..127),
// j = k within octet. Matches MFMA A/B fragment reads (contiguous 16 B,
// 2-way bank aliasing only) AND global_load_lds's base+lane*16 write rule.
// ---------------------------------------------------------------------------
__global__ __launch_bounds__(256) void k2_mfma_gemm(
    const bf16* __restrict__ A,
    const bf16* __restrict__ Wt,
    const float* __restrict__ bias,
    float* __restrict__ out)
{
    __shared__ bf16 Asl[4096];   // 4 kb * 128 m * 8 j = 8 KiB
    __shared__ bf16 Bsl[4096];   // 4 kb * 128 n * 8 j = 8 KiB

    const int tid  = threadIdx.x;
    const int w    = tid >> 6;
    const int lane = tid & 63;
    const long row0 = (long)(blockIdx.x >> 1) * 128;
    const int  n0   = (blockIdx.x & 1) * 128;

    const int wm = w & 1;        // wave m-half (0/1)
    const int wn = w >> 1;       // wave n-half (0/1)
    const int q   = lane >> 4;   // k-octet quad
    const int r16 = lane & 15;

    f32x4 acc[4][4];
#pragma unroll
    for (int i = 0; i < 4; ++i)
#pragma unroll
        for (int j = 0; j < 4; ++j) acc[i][j] = (f32x4){0.f, 0.f, 0.f, 0.f};

    const bf16* ag = A  + (row0 + lane) * (long)H + w * 8;
    const bf16* bg = Wt + (n0   + lane) * (long)H + w * 8;

    for (int kc = 0; kc < H; kc += 32) {
        // Stage A (8 KiB) + B (8 KiB): 4 global_load_lds_dwordx4 per thread.
        GLOAD_LDS16(ag + kc,           Asl + w * 1024);        // rows 0..63
        GLOAD_LDS16(ag + kc + 64 * H,  Asl + w * 1024 + 512);  // rows 64..127
        GLOAD_LDS16(bg + kc,           Bsl + w * 1024);        // cols 0..63
        GLOAD_LDS16(bg + kc + 64 * H,  Bsl + w * 1024 + 512);  // cols 64..127
        __syncthreads();

        bf16x8 afr[4], bfr[4];
#pragma unroll
        for (int t = 0; t < 4; ++t) {
            afr[t] = *(const bf16x8*)(Asl + q * 1024 + (wm * 64 + t * 16 + r16) * 8);
            bfr[t] = *(const bf16x8*)(Bsl + q * 1024 + (wn * 64 + t * 16 + r16) * 8);
        }
#pragma unroll
        for (int tm = 0; tm < 4; ++tm)
#pragma unroll
            for (int tn = 0; tn < 4; ++tn)
                acc[tm][tn] = __builtin_amdgcn_mfma_f32_16x16x32_bf16(
                    afr[tm], bfr[tn], acc[tm][tn], 0, 0, 0);
        __syncthreads();
    }

    // Epilogue: C/D layout col = lane&15, row = q*4 + reg.
#pragma unroll
    for (int tn = 0; tn < 4; ++tn) {
        const int col = n0 + wn * 64 + tn * 16 + r16;
        const float bv = bias[col];
#pragma unroll
        for (int tm = 0; tm < 4; ++tm) {
            const long rbase = row0 + wm * 64 + tm * 16 + q * 4;
#pragma unroll
            for (int r = 0; r < 4; ++r)
                out[(rbase + r) * NOUT + col] = fmaxf(acc[tm][tn][r] + bv, 0.0f);
        }
    }
}

extern "C" void kernel_launch(void* const* d_in, const int* in_sizes, int n_in,
                              void* d_out, int out_size, void* d_ws, size_t ws_size,
                              hipStream_t stream) {
    const float* x      = (const float*)d_in[0];
    const float* gamma  = (const float*)d_in[1];
    const float* beta   = (const float*)d_in[2];
    const float* attn_W = (const float*)d_in[3];
    // d_in[4] = attn_b: cancels in softmax
    const float* out_W  = (const float*)d_in[5];
    const float* out_b  = (const float*)d_in[6];
    float* out = (float*)d_out;

    bf16* fused = (bf16*)d_ws;                                  // 64 MiB
    bf16* Wt    = (bf16*)((char*)d_ws + (size_t)64 * 1024 * 1024);  // 256 KiB

    k0_convW<<<256, 64, 0, stream>>>(out_W, Wt);
    k1_ln_attn_pool<<<NROWS / 4, 256, 0, stream>>>(x, gamma, beta, attn_W, fused);
    k2_mfma_gemm<<<(NROWS / 128) * 2, 256, 0, stream>>>(fused, Wt, out_b, out);
}